// Round 7
// baseline (174.231 us; speedup 1.0000x reference)
//
#include <hip/hip_runtime.h>
#include <hip/hip_cooperative_groups.h>
#include <stdint.h>

namespace cg = cooperative_groups;

// GCN 2-layer, round 7: ONE cooperative kernel, 256 WGs x 1024 thr (1/CU),
// grid.sync() between phases. R6 lesson: per-kernel work is no longer the
// floor; 5 serialized dispatches (launch+drain each) + 391-WG imbalance were.
// B=256 buckets of NB=ceil(n/256)=391 nodes; bucket via mulhi-division,
// 9-bit local id packed with src. Fallback to 5-kernel path if cooperative
// launch fails (returns error before enqueue -> capture unaffected).
//
// Algebra: gcn_conv(x,W,b) = Agg(x) @ W + b  (Agg commutes with right-mul).
//   Agg(v)[d] = dinv[d] * ( sum_{s->d} dinv[s]*v[s] + dinv[d]*v[d] )
// Layer1 aggregates 2-wide x (64-bit packed fixed point, LDS atomics),
// layer2 aggregates scalar s = relu(Agg(x)@W1+b1)@W2 (32-bit fixed point).
// Integer accumulation => deterministic despite atomic ordering races.

#define BKT    256   // buckets == grid size
#define LBITS  9     // bits for local node id (NBv <= 512)
#define LMASK  511
#define MAXNB  512
#define MAXH   128
#define NQ     2     // int4 quads register-cached per thread in scatter

#define FP_SCALE 4194304.0f           // 2^22 (layer-1 packing)
#define FP_INV   (1.0f / 4194304.0f)
#define FP_BIAS  (1 << 25)
#define A2_SCALE 262144.0f            // 2^18 (layer-2 scalar)
#define A2_INV   (1.0f / 262144.0f)

__device__ __forceinline__ int bucket_of(int d, unsigned long long Mdiv) {
  return (int)(((unsigned long long)(unsigned)d * Mdiv) >> 42);  // exact floor(d/NBv)
}

__device__ __forceinline__ unsigned long long pack_fp(const float2 v) {
  int ix = __float2int_rn(v.x * FP_SCALE);
  int iy = __float2int_rn(v.y * FP_SCALE);
  return ((unsigned long long)(unsigned int)iy << 32) | (unsigned int)(ix + FP_BIAS);
}

// ---- phase 1: bucket the edges (reg-cached histogram scatter) ----
__device__ __forceinline__ void phase_scatter(
    const int* __restrict__ src, const int* __restrict__ dst,
    unsigned int* __restrict__ edges, int* __restrict__ cursor,
    int E, int NBv, unsigned long long Mdiv, int cap, int chunk,
    int w, int nthr, int t, int* hist, int* basec) {
  const int e0 = w * chunk;
  const int e1 = min(e0 + chunk, E);
  for (int i = t; i < BKT; i += nthr) hist[i] = 0;
  __syncthreads();
  if (chunk <= 4 * NQ * nthr) {  // register-cached path (always at this size)
    unsigned int pk[4 * NQ];
    int bk[4 * NQ];
#pragma unroll
    for (int q = 0; q < NQ; ++q) {
      const int e = e0 + 4 * (t + q * nthr);
      if (e + 3 < e1) {
        int4 s4 = *reinterpret_cast<const int4*>(src + e);
        int4 d4 = *reinterpret_cast<const int4*>(dst + e);
        int b0 = bucket_of(d4.x, Mdiv), b1_ = bucket_of(d4.y, Mdiv);
        int b2_ = bucket_of(d4.z, Mdiv), b3 = bucket_of(d4.w, Mdiv);
        bk[4*q+0] = b0; pk[4*q+0] = ((unsigned)s4.x << LBITS) | (unsigned)(d4.x - b0 * NBv);
        bk[4*q+1] = b1_; pk[4*q+1] = ((unsigned)s4.y << LBITS) | (unsigned)(d4.y - b1_ * NBv);
        bk[4*q+2] = b2_; pk[4*q+2] = ((unsigned)s4.z << LBITS) | (unsigned)(d4.z - b2_ * NBv);
        bk[4*q+3] = b3; pk[4*q+3] = ((unsigned)s4.w << LBITS) | (unsigned)(d4.w - b3 * NBv);
      } else {
#pragma unroll
        for (int j = 0; j < 4; ++j) {
          const int ee = e + j;
          if (ee < e1) {
            int d = dst[ee];
            int bb = bucket_of(d, Mdiv);
            bk[4*q+j] = bb;
            pk[4*q+j] = ((unsigned)src[ee] << LBITS) | (unsigned)(d - bb * NBv);
          } else bk[4*q+j] = -1;
        }
      }
    }
#pragma unroll
    for (int j = 0; j < 4 * NQ; ++j)
      if (bk[j] >= 0) atomicAdd(&hist[bk[j]], 1);
    __syncthreads();
    for (int i = t; i < BKT; i += nthr) {
      int c = hist[i];
      if (c > 0) basec[i] = atomicAdd(&cursor[i], c);
    }
    __syncthreads();
#pragma unroll
    for (int j = 0; j < 4 * NQ; ++j) {
      if (bk[j] >= 0) {
        int pos = atomicAdd(&basec[bk[j]], 1);
        if (pos < cap) edges[bk[j] * cap + pos] = pk[j];
      }
    }
  } else {  // generic two-pass fallback (re-reads src/dst)
    for (int e = e0 + t; e < e1; e += nthr)
      atomicAdd(&hist[bucket_of(dst[e], Mdiv)], 1);
    __syncthreads();
    for (int i = t; i < BKT; i += nthr) {
      int c = hist[i];
      if (c > 0) basec[i] = atomicAdd(&cursor[i], c);
    }
    __syncthreads();
    for (int e = e0 + t; e < e1; e += nthr) {
      int d = dst[e];
      int bb = bucket_of(d, Mdiv);
      int pos = atomicAdd(&basec[bb], 1);
      if (pos < cap)
        edges[bb * cap + pos] = ((unsigned)src[e] << LBITS) | (unsigned)(d - bb * NBv);
    }
  }
}

// ---- phase 2: per-bucket degree count + dinv + xs = dinv*x ----
__device__ __forceinline__ void phase_degscale(
    const float2* __restrict__ x, const unsigned int* __restrict__ edges,
    const int* __restrict__ cursor, int* __restrict__ deg,
    float* __restrict__ dinv, float2* __restrict__ xs,
    int n, int NBv, int cap, int b, int nthr, int t, int* cnt) {
  for (int i = t; i < NBv; i += nthr) cnt[i] = 0;
  __syncthreads();
  const int s0 = b * cap;
  const int len = min(cursor[b], cap);
  const int nv = len >> 2;
  const uint4* ev = reinterpret_cast<const uint4*>(edges + s0);
  for (int i = t; i < nv; i += nthr) {
    uint4 w = ev[i];
    atomicAdd(&cnt[w.x & LMASK], 1);
    atomicAdd(&cnt[w.y & LMASK], 1);
    atomicAdd(&cnt[w.z & LMASK], 1);
    atomicAdd(&cnt[w.w & LMASK], 1);
  }
  for (int i = (nv << 2) + t; i < len; i += nthr)
    atomicAdd(&cnt[edges[s0 + i] & LMASK], 1);
  __syncthreads();
  for (int l = t; l < NBv; l += nthr) {
    int node = b * NBv + l;
    if (node < n) {
      int c = cnt[l];
      deg[node] = c;
      float di = rsqrtf((float)(c + 1));
      dinv[node] = di;
      float2 xv = x[node];
      float2 o; o.x = di * xv.x; o.y = di * xv.y;
      xs[node] = o;
    }
  }
}

// ---- phase 3: layer-1 aggregation (packed 64b LDS atomics) + fused MLP ----
__device__ __forceinline__ void phase_agg1mlp(
    const unsigned int* __restrict__ edges, const int* __restrict__ cursor,
    const int* __restrict__ deg, const float* __restrict__ dinv,
    const float2* __restrict__ xs,
    const float* __restrict__ W1, const float* __restrict__ b1,
    const float* __restrict__ W2, float* __restrict__ ss,
    int n, int NBv, int cap, int hidden, int b, int nthr, int t,
    unsigned long long* acc, float* sW1, float* sb1, float* sW2) {
  for (int i = t; i < NBv; i += nthr) acc[i] = 0ULL;
  for (int j = t; j < 2 * hidden; j += nthr) sW1[j] = W1[j];
  for (int j = t; j < hidden; j += nthr) { sb1[j] = b1[j]; sW2[j] = W2[j]; }
  __syncthreads();
  const int s0 = b * cap;
  const int len = min(cursor[b], cap);
  const int nv = len >> 2;
  const uint4* ev = reinterpret_cast<const uint4*>(edges + s0);
  for (int i = t; i < nv; i += nthr) {
    uint4 w = ev[i];
    atomicAdd(&acc[w.x & LMASK], pack_fp(xs[w.x >> LBITS]));
    atomicAdd(&acc[w.y & LMASK], pack_fp(xs[w.y >> LBITS]));
    atomicAdd(&acc[w.z & LMASK], pack_fp(xs[w.z >> LBITS]));
    atomicAdd(&acc[w.w & LMASK], pack_fp(xs[w.w >> LBITS]));
  }
  for (int i = (nv << 2) + t; i < len; i += nthr) {
    unsigned int w = edges[s0 + i];
    atomicAdd(&acc[w & LMASK], pack_fp(xs[w >> LBITS]));
  }
  __syncthreads();
  for (int l = t; l < NBv; l += nthr) {
    int node = b * NBv + l;
    if (node < n) {
      unsigned long long p = acc[l];
      long long lo = (long long)(p & 0xffffffffULL);
      long long cntv = (long long)deg[node];
      float ax = (float)(lo - cntv * (long long)FP_BIAS) * FP_INV;
      float ay = (float)((int)(unsigned int)(p >> 32)) * FP_INV;
      float di = dinv[node];
      float2 xv = xs[node];
      float a0 = di * (ax + xv.x);
      float a1 = di * (ay + xv.y);
      float sv = 0.0f;
#pragma unroll 8
      for (int j = 0; j < hidden; ++j) {
        float h = fmaf(a0, sW1[j], fmaf(a1, sW1[hidden + j], sb1[j]));
        h = fmaxf(h, 0.0f);
        sv = fmaf(h, sW2[j], sv);
      }
      ss[node] = di * sv;
    }
  }
}

// ---- phase 4: layer-2 scalar aggregation (32b fixed LDS atomics) + out ----
__device__ __forceinline__ void phase_agg2final(
    const unsigned int* __restrict__ edges, const int* __restrict__ cursor,
    const float* __restrict__ dinv, const float* __restrict__ ss,
    const float* __restrict__ b2, float* __restrict__ out,
    int n, int NBv, int cap, int b, int nthr, int t, int* acc2) {
  for (int i = t; i < NBv; i += nthr) acc2[i] = 0;
  __syncthreads();
  const int s0 = b * cap;
  const int len = min(cursor[b], cap);
  const int nv = len >> 2;
  const uint4* ev = reinterpret_cast<const uint4*>(edges + s0);
  for (int i = t; i < nv; i += nthr) {
    uint4 w = ev[i];
    atomicAdd(&acc2[w.x & LMASK], __float2int_rn(ss[w.x >> LBITS] * A2_SCALE));
    atomicAdd(&acc2[w.y & LMASK], __float2int_rn(ss[w.y >> LBITS] * A2_SCALE));
    atomicAdd(&acc2[w.z & LMASK], __float2int_rn(ss[w.z >> LBITS] * A2_SCALE));
    atomicAdd(&acc2[w.w & LMASK], __float2int_rn(ss[w.w >> LBITS] * A2_SCALE));
  }
  for (int i = (nv << 2) + t; i < len; i += nthr) {
    unsigned int w = edges[s0 + i];
    atomicAdd(&acc2[w & LMASK], __float2int_rn(ss[w >> LBITS] * A2_SCALE));
  }
  __syncthreads();
  for (int l = t; l < NBv; l += nthr) {
    int node = b * NBv + l;
    if (node < n)
      out[node] = dinv[node] * ((float)acc2[l] * A2_INV + ss[node]) + b2[0];
  }
}

// ---- fused cooperative kernel ----
static __global__ __launch_bounds__(1024) void k_fused(
    const float2* x, const int* src, const int* dst,
    const float* W1, const float* b1, const float* W2, const float* b2,
    float* out, int n, int E, int NBv, unsigned long long Mdiv,
    int cap, int chunk, int hidden, int* cursor, unsigned int* edges,
    int* deg, float* dinv, float2* xs, float* ss) {
  __shared__ int hist[BKT];
  __shared__ int basec[BKT];
  __shared__ int cnt[MAXNB];
  __shared__ unsigned long long acc[MAXNB];
  __shared__ int acc2[MAXNB];
  __shared__ float sW1[2 * MAXH];
  __shared__ float sb1[MAXH];
  __shared__ float sW2[MAXH];
  cg::grid_group grid = cg::this_grid();
  const int t = threadIdx.x, b = blockIdx.x, nthr = blockDim.x;
  if (t == 0) cursor[b] = 0;
  grid.sync();
  phase_scatter(src, dst, edges, cursor, E, NBv, Mdiv, cap, chunk, b, nthr, t, hist, basec);
  grid.sync();
  phase_degscale(x, edges, cursor, deg, dinv, xs, n, NBv, cap, b, nthr, t, cnt);
  grid.sync();
  phase_agg1mlp(edges, cursor, deg, dinv, xs, W1, b1, W2, ss, n, NBv, cap, hidden,
                b, nthr, t, acc, sW1, sb1, sW2);
  grid.sync();
  phase_agg2final(edges, cursor, dinv, ss, b2, out, n, NBv, cap, b, nthr, t, acc2);
}

// ---- fallback: 5-kernel pipeline from the same phase functions ----
static __global__ void k_init(int* __restrict__ cursor) {
  if (threadIdx.x < BKT) cursor[threadIdx.x] = 0;
}
static __global__ __launch_bounds__(1024) void k_scatter_s(
    const int* src, const int* dst, unsigned int* edges, int* cursor,
    int E, int NBv, unsigned long long Mdiv, int cap, int chunk) {
  __shared__ int hist[BKT];
  __shared__ int basec[BKT];
  phase_scatter(src, dst, edges, cursor, E, NBv, Mdiv, cap, chunk,
                blockIdx.x, blockDim.x, threadIdx.x, hist, basec);
}
static __global__ __launch_bounds__(1024) void k_degscale_s(
    const float2* x, const unsigned int* edges, const int* cursor,
    int* deg, float* dinv, float2* xs, int n, int NBv, int cap) {
  __shared__ int cnt[MAXNB];
  phase_degscale(x, edges, cursor, deg, dinv, xs, n, NBv, cap,
                 blockIdx.x, blockDim.x, threadIdx.x, cnt);
}
static __global__ __launch_bounds__(1024) void k_agg1mlp_s(
    const unsigned int* edges, const int* cursor, const int* deg,
    const float* dinv, const float2* xs, const float* W1, const float* b1,
    const float* W2, float* ss, int n, int NBv, int cap, int hidden) {
  __shared__ unsigned long long acc[MAXNB];
  __shared__ float sW1[2 * MAXH];
  __shared__ float sb1[MAXH];
  __shared__ float sW2[MAXH];
  phase_agg1mlp(edges, cursor, deg, dinv, xs, W1, b1, W2, ss, n, NBv, cap, hidden,
                blockIdx.x, blockDim.x, threadIdx.x, acc, sW1, sb1, sW2);
}
static __global__ __launch_bounds__(1024) void k_agg2final_s(
    const unsigned int* edges, const int* cursor, const float* dinv,
    const float* ss, const float* b2, float* out, int n, int NBv, int cap) {
  __shared__ int acc2[MAXNB];
  phase_agg2final(edges, cursor, dinv, ss, b2, out, n, NBv, cap,
                  blockIdx.x, blockDim.x, threadIdx.x, acc2);
}

extern "C" void kernel_launch(void* const* d_in, const int* in_sizes, int n_in,
                              void* d_out, int out_size, void* d_ws, size_t ws_size,
                              hipStream_t stream) {
  const float2* x = (const float2*)d_in[0];
  const int*   ei = (const int*)d_in[1];
  const float* W1 = (const float*)d_in[2];
  const float* b1 = (const float*)d_in[3];
  const float* W2 = (const float*)d_in[4];
  const float* b2 = (const float*)d_in[5];

  int n = in_sizes[0] / 2;         // x is [n,2]
  int E = in_sizes[1] / 2;         // edge_index is [2,E]
  int hidden = in_sizes[3];        // b1 is [hidden]
  const int* src = ei;
  const int* dst = ei + E;
  float* out = (float*)d_out;

  int NBv = (n + BKT - 1) / BKT;   // 391 @ n=100K  (<= MAXNB for n <= 131072)
  unsigned long long Mdiv = ((1ULL << 42) + (unsigned long long)NBv - 1) / (unsigned long long)NBv;
  int chunk = ((E + BKT - 1) / BKT + 3) & ~3;
  int mean = E / BKT;
  int cap = (mean + mean / 8 + 512 + 3) & ~3;

  // ws layout: cursor[BKT] | deg[n] | dinv[n] | ss[n] | xs[2n] | edges[BKT*cap]
  char* ws = (char*)d_ws;
  int*   cursor = (int*)ws;
  int*   deg    = (int*)(ws + 4LL * BKT);
  float* dinv   = (float*)(ws + 4LL * BKT + 4LL * n);
  float* ss     = (float*)(ws + 4LL * BKT + 8LL * n);
  float2* xs    = (float2*)(ws + 4LL * BKT + 12LL * n);
  size_t eoff = (4LL * BKT + 20LL * n + 15) & ~15LL;
  unsigned int* edges = (unsigned int*)(ws + eoff);
  if (eoff + 4LL * BKT * cap > ws_size)
    cap = (int)(((ws_size - eoff) / (4LL * BKT)) & ~3LL);

  void* args[] = {(void*)&x, (void*)&src, (void*)&dst, (void*)&W1, (void*)&b1,
                  (void*)&W2, (void*)&b2, (void*)&out, (void*)&n, (void*)&E,
                  (void*)&NBv, (void*)&Mdiv, (void*)&cap, (void*)&chunk,
                  (void*)&hidden, (void*)&cursor, (void*)&edges, (void*)&deg,
                  (void*)&dinv, (void*)&xs, (void*)&ss};
  hipError_t err = hipLaunchCooperativeKernel((const void*)k_fused, dim3(BKT),
                                              dim3(1024), args, 0, stream);
  if (err != hipSuccess) {
    // fallback: proven 5-kernel pipeline (same phase functions)
    k_init<<<1, BKT, 0, stream>>>(cursor);
    k_scatter_s<<<BKT, 1024, 0, stream>>>(src, dst, edges, cursor, E, NBv, Mdiv, cap, chunk);
    k_degscale_s<<<BKT, 1024, 0, stream>>>(x, edges, cursor, deg, dinv, xs, n, NBv, cap);
    k_agg1mlp_s<<<BKT, 1024, 0, stream>>>(edges, cursor, deg, dinv, xs, W1, b1, W2, ss, n, NBv, cap, hidden);
    k_agg2final_s<<<BKT, 1024, 0, stream>>>(edges, cursor, dinv, ss, b2, out, n, NBv, cap);
  }
}

// Round 8
// 51.176 us; speedup vs baseline: 3.4046x; 3.4046x over previous
//
#include <hip/hip_runtime.h>
#include <stdint.h>

// GCN 2-layer, round 8: 5-kernel pipeline (R6 structure) with R7's balanced
// geometry: B=256 buckets (NBv=ceil(n/256)=391) -> exactly 1 WG/CU on every
// consumer phase (R6 had 391 WGs on 256 CUs = 2-round makespan).
// R7 lesson (counter-verified): cooperative grid.sync() on 8 non-coherent
// XCD L2s costs ~25-30us/sync -> fused kernel 151us vs 5-kernel ~40us work.
// Kernel boundaries ARE the cheap device-wide barrier here.
//
// Algebra: gcn_conv(x,W,b) = Agg(x) @ W + b  (Agg commutes with right-mul).
//   Agg(v)[d] = dinv[d] * ( sum_{s->d} dinv[s]*v[s] + dinv[d]*v[d] )
// Layer1 aggregates 2-wide x (64-bit packed fixed point, LDS atomics),
// layer2 aggregates scalar s = relu(Agg(x)@W1+b1)@W2 (32-bit fixed point).
// Integer accumulation => deterministic despite atomic ordering races.

#define BKT    256   // buckets == consumer grid size (1 WG/CU)
#define LBITS  9     // bits for local node id (NBv <= 512)
#define LMASK  511
#define MAXNB  512
#define MAXH   128
#define NQ     2     // int4 quads register-cached per thread in scatter

#define FP_SCALE 4194304.0f           // 2^22 (layer-1 packing)
#define FP_INV   (1.0f / 4194304.0f)
#define FP_BIAS  (1 << 25)
#define A2_SCALE 262144.0f            // 2^18 (layer-2 scalar)
#define A2_INV   (1.0f / 262144.0f)

__device__ __forceinline__ int bucket_of(int d, unsigned long long Mdiv) {
  return (int)(((unsigned long long)(unsigned)d * Mdiv) >> 42);  // exact floor(d/NBv)
}

__device__ __forceinline__ unsigned long long pack_fp(const float2 v) {
  int ix = __float2int_rn(v.x * FP_SCALE);
  int iy = __float2int_rn(v.y * FP_SCALE);
  return ((unsigned long long)(unsigned int)iy << 32) | (unsigned int)(ix + FP_BIAS);
}

static __global__ void k_init(int* __restrict__ cursor) {
  if (threadIdx.x < BKT) cursor[threadIdx.x] = 0;
}

// Bucket the edge list. Each WG: int4-load its chunk into registers (packed
// word + bucket id, statically indexed slots), LDS histogram -> one global
// reservation per touched bucket -> scatter from registers.
static __global__ __launch_bounds__(1024) void
k_scatter(const int* __restrict__ src, const int* __restrict__ dst,
          unsigned int* __restrict__ edges, int* __restrict__ cursor,
          int E, int NBv, unsigned long long Mdiv, int cap, int chunk) {
  __shared__ int hist[BKT];
  __shared__ int basec[BKT];
  const int t = threadIdx.x;
  const int nthr = blockDim.x;
  const int e0 = blockIdx.x * chunk;          // chunk % 4 == 0
  const int e1 = min(e0 + chunk, E);
  for (int i = t; i < BKT; i += nthr) hist[i] = 0;
  __syncthreads();

  unsigned int pk[4 * NQ];                    // packed (src<<9 | local)
  int bk[4 * NQ];                             // bucket id, -1 = invalid
#pragma unroll
  for (int q = 0; q < NQ; ++q) {
    const int e = e0 + 4 * (t + q * 1024);
    if (e + 3 < e1) {
      int4 s4 = *reinterpret_cast<const int4*>(src + e);
      int4 d4 = *reinterpret_cast<const int4*>(dst + e);
      int b0 = bucket_of(d4.x, Mdiv), b1_ = bucket_of(d4.y, Mdiv);
      int b2_ = bucket_of(d4.z, Mdiv), b3 = bucket_of(d4.w, Mdiv);
      bk[4*q+0] = b0;  pk[4*q+0] = ((unsigned)s4.x << LBITS) | (unsigned)(d4.x - b0 * NBv);
      bk[4*q+1] = b1_; pk[4*q+1] = ((unsigned)s4.y << LBITS) | (unsigned)(d4.y - b1_ * NBv);
      bk[4*q+2] = b2_; pk[4*q+2] = ((unsigned)s4.z << LBITS) | (unsigned)(d4.z - b2_ * NBv);
      bk[4*q+3] = b3;  pk[4*q+3] = ((unsigned)s4.w << LBITS) | (unsigned)(d4.w - b3 * NBv);
    } else {
#pragma unroll
      for (int j = 0; j < 4; ++j) {
        const int ee = e + j;
        if (ee < e1) {
          int d = dst[ee];
          int bb = bucket_of(d, Mdiv);
          bk[4*q+j] = bb;
          pk[4*q+j] = ((unsigned)src[ee] << LBITS) | (unsigned)(d - bb * NBv);
        } else bk[4*q+j] = -1;
      }
    }
  }
#pragma unroll
  for (int j = 0; j < 4 * NQ; ++j)
    if (bk[j] >= 0) atomicAdd(&hist[bk[j]], 1);
  __syncthreads();
  for (int i = t; i < BKT; i += nthr) {
    int c = hist[i];
    if (c > 0) basec[i] = atomicAdd(&cursor[i], c);
  }
  __syncthreads();
#pragma unroll
  for (int j = 0; j < 4 * NQ; ++j) {
    if (bk[j] >= 0) {
      int pos = atomicAdd(&basec[bk[j]], 1);
      if (pos < cap)  // overflow guard (statistically unreachable)
        edges[bk[j] * cap + pos] = pk[j];
    }
  }
}

// Per-bucket: count in-degrees in LDS, then deg/dinv/xs for owned nodes.
static __global__ __launch_bounds__(1024) void
k_degscale(const float2* __restrict__ x, const unsigned int* __restrict__ edges,
           const int* __restrict__ cursor, int* __restrict__ deg,
           float* __restrict__ dinv, float2* __restrict__ xs,
           int n, int NBv, int cap) {
  __shared__ int cnt[MAXNB];
  const int b = blockIdx.x, t = threadIdx.x, nthr = blockDim.x;
  for (int i = t; i < NBv; i += nthr) cnt[i] = 0;
  __syncthreads();
  const int s0 = b * cap;
  const int len = min(cursor[b], cap);
  const int nv = len >> 2;
  const uint4* ev = reinterpret_cast<const uint4*>(edges + s0);
  for (int i = t; i < nv; i += nthr) {
    uint4 w = ev[i];
    atomicAdd(&cnt[w.x & LMASK], 1);
    atomicAdd(&cnt[w.y & LMASK], 1);
    atomicAdd(&cnt[w.z & LMASK], 1);
    atomicAdd(&cnt[w.w & LMASK], 1);
  }
  for (int i = (nv << 2) + t; i < len; i += nthr)
    atomicAdd(&cnt[edges[s0 + i] & LMASK], 1);
  __syncthreads();
  for (int l = t; l < NBv; l += nthr) {
    int node = b * NBv + l;
    if (node < n) {
      int c = cnt[l];
      deg[node] = c;
      float di = rsqrtf((float)(c + 1));
      dinv[node] = di;
      float2 xv = x[node];
      float2 o; o.x = di * xv.x; o.y = di * xv.y;
      xs[node] = o;
    }
  }
}

// Per-bucket: layer-1 aggregation (packed 64b LDS atomics) + fused MLP
// epilogue producing ss = dinv * (relu(Agg(x)@W1+b1) @ W2).
static __global__ __launch_bounds__(1024) void
k_agg1mlp(const unsigned int* __restrict__ edges, const int* __restrict__ cursor,
          const int* __restrict__ deg, const float* __restrict__ dinv,
          const float2* __restrict__ xs,
          const float* __restrict__ W1, const float* __restrict__ b1,
          const float* __restrict__ W2, float* __restrict__ ss,
          int n, int NBv, int cap, int hidden) {
  __shared__ unsigned long long acc[MAXNB];
  __shared__ float sW1[2 * MAXH];
  __shared__ float sb1[MAXH];
  __shared__ float sW2[MAXH];
  const int b = blockIdx.x, t = threadIdx.x, nthr = blockDim.x;
  for (int i = t; i < NBv; i += nthr) acc[i] = 0ULL;
  for (int j = t; j < 2 * hidden; j += nthr) sW1[j] = W1[j];
  for (int j = t; j < hidden; j += nthr) { sb1[j] = b1[j]; sW2[j] = W2[j]; }
  __syncthreads();
  const int s0 = b * cap;
  const int len = min(cursor[b], cap);
  const int nv = len >> 2;
  const uint4* ev = reinterpret_cast<const uint4*>(edges + s0);
  for (int i = t; i < nv; i += nthr) {
    uint4 w = ev[i];
    atomicAdd(&acc[w.x & LMASK], pack_fp(xs[w.x >> LBITS]));
    atomicAdd(&acc[w.y & LMASK], pack_fp(xs[w.y >> LBITS]));
    atomicAdd(&acc[w.z & LMASK], pack_fp(xs[w.z >> LBITS]));
    atomicAdd(&acc[w.w & LMASK], pack_fp(xs[w.w >> LBITS]));
  }
  for (int i = (nv << 2) + t; i < len; i += nthr) {
    unsigned int w = edges[s0 + i];
    atomicAdd(&acc[w & LMASK], pack_fp(xs[w >> LBITS]));
  }
  __syncthreads();
  for (int l = t; l < NBv; l += nthr) {
    int node = b * NBv + l;
    if (node < n) {
      unsigned long long p = acc[l];
      long long lo = (long long)(p & 0xffffffffULL);
      long long cntv = (long long)deg[node];
      float ax = (float)(lo - cntv * (long long)FP_BIAS) * FP_INV;
      float ay = (float)((int)(unsigned int)(p >> 32)) * FP_INV;
      float di = dinv[node];
      float2 xv = xs[node];
      float a0 = di * (ax + xv.x);
      float a1 = di * (ay + xv.y);
      float sv = 0.0f;
#pragma unroll 8
      for (int j = 0; j < hidden; ++j) {
        float h = fmaf(a0, sW1[j], fmaf(a1, sW1[hidden + j], sb1[j]));
        h = fmaxf(h, 0.0f);
        sv = fmaf(h, sW2[j], sv);
      }
      ss[node] = di * sv;
    }
  }
}

// Per-bucket: layer-2 scalar aggregation (32b fixed LDS atomics) + output.
static __global__ __launch_bounds__(1024) void
k_agg2final(const unsigned int* __restrict__ edges, const int* __restrict__ cursor,
            const float* __restrict__ dinv, const float* __restrict__ ss,
            const float* __restrict__ b2, float* __restrict__ out,
            int n, int NBv, int cap) {
  __shared__ int acc2[MAXNB];
  const int b = blockIdx.x, t = threadIdx.x, nthr = blockDim.x;
  for (int i = t; i < NBv; i += nthr) acc2[i] = 0;
  __syncthreads();
  const int s0 = b * cap;
  const int len = min(cursor[b], cap);
  const int nv = len >> 2;
  const uint4* ev = reinterpret_cast<const uint4*>(edges + s0);
  for (int i = t; i < nv; i += nthr) {
    uint4 w = ev[i];
    atomicAdd(&acc2[w.x & LMASK], __float2int_rn(ss[w.x >> LBITS] * A2_SCALE));
    atomicAdd(&acc2[w.y & LMASK], __float2int_rn(ss[w.y >> LBITS] * A2_SCALE));
    atomicAdd(&acc2[w.z & LMASK], __float2int_rn(ss[w.z >> LBITS] * A2_SCALE));
    atomicAdd(&acc2[w.w & LMASK], __float2int_rn(ss[w.w >> LBITS] * A2_SCALE));
  }
  for (int i = (nv << 2) + t; i < len; i += nthr) {
    unsigned int w = edges[s0 + i];
    atomicAdd(&acc2[w & LMASK], __float2int_rn(ss[w >> LBITS] * A2_SCALE));
  }
  __syncthreads();
  for (int l = t; l < NBv; l += nthr) {
    int node = b * NBv + l;
    if (node < n)
      out[node] = dinv[node] * ((float)acc2[l] * A2_INV + ss[node]) + b2[0];
  }
}

extern "C" void kernel_launch(void* const* d_in, const int* in_sizes, int n_in,
                              void* d_out, int out_size, void* d_ws, size_t ws_size,
                              hipStream_t stream) {
  const float2* x = (const float2*)d_in[0];
  const int*   ei = (const int*)d_in[1];
  const float* W1 = (const float*)d_in[2];
  const float* b1 = (const float*)d_in[3];
  const float* W2 = (const float*)d_in[4];
  const float* b2 = (const float*)d_in[5];

  int n = in_sizes[0] / 2;         // x is [n,2]
  int E = in_sizes[1] / 2;         // edge_index is [2,E]
  int hidden = in_sizes[3];        // b1 is [hidden]
  const int* src = ei;
  const int* dst = ei + E;
  float* out = (float*)d_out;

  int NBv = (n + BKT - 1) / BKT;   // 391 @ n=100K  (<= MAXNB for n <= 131072)
  unsigned long long Mdiv =
      ((1ULL << 42) + (unsigned long long)NBv - 1) / (unsigned long long)NBv;
  int chunk = ((E + BKT - 1) / BKT + 3) & ~3;   // <= 4*NQ*1024 for E<=2.09M
  int mean = E / BKT;
  int cap = (mean + mean / 8 + 512 + 3) & ~3;

  // ws layout: cursor[BKT] | deg[n] | dinv[n] | ss[n] | xs[2n] | edges[BKT*cap]
  char* ws = (char*)d_ws;
  int*   cursor = (int*)ws;
  int*   deg    = (int*)(ws + 4LL * BKT);
  float* dinv   = (float*)(ws + 4LL * BKT + 4LL * n);
  float* ss     = (float*)(ws + 4LL * BKT + 8LL * n);
  float2* xs    = (float2*)(ws + 4LL * BKT + 12LL * n);
  size_t eoff = (4LL * BKT + 20LL * n + 15) & ~15LL;
  unsigned int* edges = (unsigned int*)(ws + eoff);
  if (eoff + 4LL * BKT * cap > ws_size)
    cap = (int)(((ws_size - eoff) / (4LL * BKT)) & ~3LL);

  k_init<<<1, BKT, 0, stream>>>(cursor);
  k_scatter<<<BKT, 1024, 0, stream>>>(src, dst, edges, cursor, E, NBv, Mdiv, cap, chunk);
  k_degscale<<<BKT, 1024, 0, stream>>>(x, edges, cursor, deg, dinv, xs, n, NBv, cap);
  k_agg1mlp<<<BKT, 1024, 0, stream>>>(edges, cursor, deg, dinv, xs, W1, b1, W2, ss, n, NBv, cap, hidden);
  k_agg2final<<<BKT, 1024, 0, stream>>>(edges, cursor, dinv, ss, b2, out, n, NBv, cap);
}

// Round 9
// 39.323 us; speedup vs baseline: 4.4308x; 1.3014x over previous
//
#include <hip/hip_runtime.h>
#include <stdint.h>

// GCN 2-layer, round 9: cursor-free fixed-slot bucketing. 4 dispatches,
// ZERO global atomics anywhere in the pipeline.
//   k_scatter: LDS-stage edges per bucket, sentinel-pad to x4, flush with
//              coalesced uint4 stores into fixed [bucket][wg][S=64] slots,
//              record run lengths in cnt2[bucket][wg].
//   k_degscale / k_agg1mlp / k_agg2final: per-bucket consumers scan exact
//              runs via cnt2 (4 threads per run), LDS-atomic aggregation.
// Lessons embedded: R7: grid.sync costs ~27us/sync on 8 non-coherent XCD L2s
//   -> kernel boundaries are the cheap barrier. R5/R8: work per phase is tiny
//   (6.3K edges/CU); floor was node count + 65K reservation atomics (~3.5us)
//   + 6.3K scalar 4B stores/CU (~2.6us). All three removed here.
//
// Algebra: gcn_conv(x,W,b) = Agg(x) @ W + b  (Agg commutes with right-mul).
//   Agg(v)[d] = dinv[d] * ( sum_{s->d} dinv[s]*v[s] + dinv[d]*v[d] )
// Layer1 aggregates 2-wide x (64-bit packed fixed point, LDS atomics),
// layer2 aggregates scalar s = relu(Agg(x)@W1+b1)@W2 (32-bit fixed point).
// Integer accumulation => deterministic despite atomic ordering races.
// Sentinel edges (src=0, local=511) land in acc[511]/cnt[511]: never read.

#define BKT    256   // buckets == grid size (1 WG/CU), also scatter WG count
#define LBITS  9     // bits for local node id (NBv <= 511)
#define LMASK  511
#define MAXNB  512
#define MAXH   128
#define NQ     2     // int4 quads register-cached per thread in scatter
#define SSTR   68    // LDS stage stride (u32) per bucket: 272B = 16B-aligned,
                     // 68%32=4 -> bank pattern varies per bucket (no hotspot)
#define SENTV  511u  // sentinel packed edge: src=0, local=511

#define FP_SCALE 4194304.0f           // 2^22 (layer-1 packing)
#define FP_INV   (1.0f / 4194304.0f)
#define FP_BIAS  (1 << 25)
#define A2_SCALE 262144.0f            // 2^18 (layer-2 scalar)
#define A2_INV   (1.0f / 262144.0f)

__device__ __forceinline__ int bucket_of(int d, unsigned long long Mdiv) {
  return (int)(((unsigned long long)(unsigned)d * Mdiv) >> 42);  // floor(d/NBv)
}

__device__ __forceinline__ unsigned long long pack_fp(const float2 v) {
  int ix = __float2int_rn(v.x * FP_SCALE);
  int iy = __float2int_rn(v.y * FP_SCALE);
  return ((unsigned long long)(unsigned int)iy << 32) | (unsigned int)(ix + FP_BIAS);
}

// ---- k_scatter: bucket edges into fixed slots, no global atomics ----
static __global__ __launch_bounds__(1024) void
k_scatter(const int* __restrict__ src, const int* __restrict__ dst,
          unsigned int* __restrict__ edges, unsigned int* __restrict__ cnt2,
          int E, int NBv, unsigned long long Mdiv, int S, int chunk) {
  __shared__ unsigned int stage[BKT * SSTR];   // ~70 KB (gfx950 allows 160)
  __shared__ int cntL[BKT];
  const int t = threadIdx.x, w = blockIdx.x;
  if (t < BKT) cntL[t] = 0;
  __syncthreads();

  const int e0 = w * chunk;                    // chunk % 4 == 0
  const int e1 = min(e0 + chunk, E);
  unsigned int pk[4 * NQ];                     // packed (src<<9 | local_dst)
  int bk[4 * NQ];                              // bucket id, -1 = invalid
#pragma unroll
  for (int q = 0; q < NQ; ++q) {
    const int e = e0 + 4 * (t + q * 1024);
    if (e + 3 < e1) {
      int4 s4 = *reinterpret_cast<const int4*>(src + e);
      int4 d4 = *reinterpret_cast<const int4*>(dst + e);
      int b0 = bucket_of(d4.x, Mdiv), b1_ = bucket_of(d4.y, Mdiv);
      int b2_ = bucket_of(d4.z, Mdiv), b3 = bucket_of(d4.w, Mdiv);
      bk[4*q+0] = b0;  pk[4*q+0] = ((unsigned)s4.x << LBITS) | (unsigned)(d4.x - b0 * NBv);
      bk[4*q+1] = b1_; pk[4*q+1] = ((unsigned)s4.y << LBITS) | (unsigned)(d4.y - b1_ * NBv);
      bk[4*q+2] = b2_; pk[4*q+2] = ((unsigned)s4.z << LBITS) | (unsigned)(d4.z - b2_ * NBv);
      bk[4*q+3] = b3;  pk[4*q+3] = ((unsigned)s4.w << LBITS) | (unsigned)(d4.w - b3 * NBv);
    } else {
#pragma unroll
      for (int j = 0; j < 4; ++j) {
        const int ee = e + j;
        if (ee < e1) {
          int d = dst[ee];
          int bb = bucket_of(d, Mdiv);
          bk[4*q+j] = bb;
          pk[4*q+j] = ((unsigned)src[ee] << LBITS) | (unsigned)(d - bb * NBv);
        } else bk[4*q+j] = -1;
      }
    }
  }
  // stage into per-bucket LDS runs
#pragma unroll
  for (int j = 0; j < 4 * NQ; ++j) {
    if (bk[j] >= 0) {
      int p = atomicAdd(&cntL[bk[j]], 1);
      if (p < S) stage[bk[j] * SSTR + p] = pk[j];  // overflow (~never): drop
    }
  }
  __syncthreads();
  // record counts, sentinel-pad each run to a multiple of 4
  if (t < BKT) {
    int c = min(cntL[t], S);
    cnt2[t * BKT + w] = (unsigned)c;
    int c4e = (c + 3) & ~3;
    for (int j = c; j < c4e; ++j) stage[t * SSTR + j] = SENTV;
    cntL[t] = c4e;
  }
  __syncthreads();
  // coalesced uint4 flush: 4 threads per bucket run
  const int i = t >> 2, sub = t & 3;
  const int c4 = cntL[i] >> 2;
  unsigned int* gdst = edges + (size_t)(i * BKT + w) * (size_t)S;
  const uint4* ls = reinterpret_cast<const uint4*>(stage + i * SSTR);
  for (int k = sub; k < c4; k += 4)
    *reinterpret_cast<uint4*>(gdst + (k << 2)) = ls[k];
}

// ---- k_degscale: per-bucket degree count + dinv + xs = dinv*x ----
static __global__ __launch_bounds__(1024) void
k_degscale(const float2* __restrict__ x, const unsigned int* __restrict__ edges,
           const unsigned int* __restrict__ cnt2, int* __restrict__ deg,
           float* __restrict__ dinv, float2* __restrict__ xs,
           int n, int NBv, int S) {
  __shared__ int cnt[MAXNB];
  const int b = blockIdx.x, t = threadIdx.x;
  if (t < MAXNB) cnt[t] = 0;
  __syncthreads();
  const int wrun = t >> 2, sub = t & 3;
  const int c4 = ((int)cnt2[b * BKT + wrun] + 3) >> 2;
  const uint4* run = reinterpret_cast<const uint4*>(
      edges + (size_t)(b * BKT + wrun) * (size_t)S);
  for (int k = sub; k < c4; k += 4) {
    uint4 v = run[k];
    atomicAdd(&cnt[v.x & LMASK], 1);
    atomicAdd(&cnt[v.y & LMASK], 1);
    atomicAdd(&cnt[v.z & LMASK], 1);
    atomicAdd(&cnt[v.w & LMASK], 1);
  }
  __syncthreads();
  for (int l = t; l < NBv; l += 1024) {
    int node = b * NBv + l;
    if (node < n) {
      int c = cnt[l];
      deg[node] = c;
      float di = rsqrtf((float)(c + 1));
      dinv[node] = di;
      float2 xv = x[node];
      float2 o; o.x = di * xv.x; o.y = di * xv.y;
      xs[node] = o;
    }
  }
}

// ---- k_agg1mlp: layer-1 aggregation (64b packed LDS atomics) + MLP ----
static __global__ __launch_bounds__(1024) void
k_agg1mlp(const unsigned int* __restrict__ edges, const unsigned int* __restrict__ cnt2,
          const int* __restrict__ deg, const float* __restrict__ dinv,
          const float2* __restrict__ xs,
          const float* __restrict__ W1, const float* __restrict__ b1,
          const float* __restrict__ W2, float* __restrict__ ss,
          int n, int NBv, int S, int hidden) {
  __shared__ unsigned long long acc[MAXNB];
  __shared__ float sW1[2 * MAXH];
  __shared__ float sb1[MAXH];
  __shared__ float sW2[MAXH];
  const int b = blockIdx.x, t = threadIdx.x;
  if (t < MAXNB) acc[t] = 0ULL;
  for (int j = t; j < 2 * hidden; j += 1024) sW1[j] = W1[j];
  for (int j = t; j < hidden; j += 1024) { sb1[j] = b1[j]; sW2[j] = W2[j]; }
  __syncthreads();
  const int wrun = t >> 2, sub = t & 3;
  const int c4 = ((int)cnt2[b * BKT + wrun] + 3) >> 2;
  const uint4* run = reinterpret_cast<const uint4*>(
      edges + (size_t)(b * BKT + wrun) * (size_t)S);
  for (int k = sub; k < c4; k += 4) {
    uint4 v = run[k];
    atomicAdd(&acc[v.x & LMASK], pack_fp(xs[v.x >> LBITS]));
    atomicAdd(&acc[v.y & LMASK], pack_fp(xs[v.y >> LBITS]));
    atomicAdd(&acc[v.z & LMASK], pack_fp(xs[v.z >> LBITS]));
    atomicAdd(&acc[v.w & LMASK], pack_fp(xs[v.w >> LBITS]));
  }
  __syncthreads();
  for (int l = t; l < NBv; l += 1024) {
    int node = b * NBv + l;
    if (node < n) {
      unsigned long long p = acc[l];
      long long lo = (long long)(p & 0xffffffffULL);
      long long cntv = (long long)deg[node];
      float ax = (float)(lo - cntv * (long long)FP_BIAS) * FP_INV;
      float ay = (float)((int)(unsigned int)(p >> 32)) * FP_INV;
      float di = dinv[node];
      float2 xv = xs[node];
      float a0 = di * (ax + xv.x);
      float a1 = di * (ay + xv.y);
      float sv = 0.0f;
#pragma unroll 8
      for (int j = 0; j < hidden; ++j) {
        float h = fmaf(a0, sW1[j], fmaf(a1, sW1[hidden + j], sb1[j]));
        h = fmaxf(h, 0.0f);
        sv = fmaf(h, sW2[j], sv);
      }
      ss[node] = di * sv;
    }
  }
}

// ---- k_agg2final: layer-2 scalar aggregation (32b LDS atomics) + out ----
static __global__ __launch_bounds__(1024) void
k_agg2final(const unsigned int* __restrict__ edges, const unsigned int* __restrict__ cnt2,
            const float* __restrict__ dinv, const float* __restrict__ ss,
            const float* __restrict__ b2, float* __restrict__ out,
            int n, int NBv, int S) {
  __shared__ int acc2[MAXNB];
  const int b = blockIdx.x, t = threadIdx.x;
  if (t < MAXNB) acc2[t] = 0;
  __syncthreads();
  const int wrun = t >> 2, sub = t & 3;
  const int c4 = ((int)cnt2[b * BKT + wrun] + 3) >> 2;
  const uint4* run = reinterpret_cast<const uint4*>(
      edges + (size_t)(b * BKT + wrun) * (size_t)S);
  for (int k = sub; k < c4; k += 4) {
    uint4 v = run[k];
    atomicAdd(&acc2[v.x & LMASK], __float2int_rn(ss[v.x >> LBITS] * A2_SCALE));
    atomicAdd(&acc2[v.y & LMASK], __float2int_rn(ss[v.y >> LBITS] * A2_SCALE));
    atomicAdd(&acc2[v.z & LMASK], __float2int_rn(ss[v.z >> LBITS] * A2_SCALE));
    atomicAdd(&acc2[v.w & LMASK], __float2int_rn(ss[v.w >> LBITS] * A2_SCALE));
  }
  __syncthreads();
  for (int l = t; l < NBv; l += 1024) {
    int node = b * NBv + l;
    if (node < n)
      out[node] = dinv[node] * ((float)acc2[l] * A2_INV + ss[node]) + b2[0];
  }
}

extern "C" void kernel_launch(void* const* d_in, const int* in_sizes, int n_in,
                              void* d_out, int out_size, void* d_ws, size_t ws_size,
                              hipStream_t stream) {
  const float2* x = (const float2*)d_in[0];
  const int*   ei = (const int*)d_in[1];
  const float* W1 = (const float*)d_in[2];
  const float* b1 = (const float*)d_in[3];
  const float* W2 = (const float*)d_in[4];
  const float* b2 = (const float*)d_in[5];

  int n = in_sizes[0] / 2;         // x is [n,2]
  int E = in_sizes[1] / 2;         // edge_index is [2,E]
  int hidden = in_sizes[3];        // b1 is [hidden]
  const int* src = ei;
  const int* dst = ei + E;
  float* out = (float*)d_out;

  int NBv = (n + BKT - 1) / BKT;   // 391 @ n=100K (sentinel 511 > NBv needed)
  unsigned long long Mdiv =
      ((1ULL << 42) + (unsigned long long)NBv - 1) / (unsigned long long)NBv;
  int chunk = ((E + BKT - 1) / BKT + 3) & ~3;   // 6252 @ E=1.6M (<= 8192 cache)

  // ws layout: cnt2[BKT*BKT] | deg[n] | dinv[n] | ss[n] | xs[2n] | edges
  char* ws = (char*)d_ws;
  unsigned int* cnt2 = (unsigned int*)ws;                         // 256 KB
  int*   deg  = (int*)(ws + 4LL * BKT * BKT);
  float* dinv = (float*)(ws + 4LL * BKT * BKT + 4LL * n);
  float* ss   = (float*)(ws + 4LL * BKT * BKT + 8LL * n);
  float2* xs  = (float2*)(ws + 4LL * BKT * BKT + 12LL * n);
  size_t eoff = (4LL * BKT * BKT + 20LL * n + 255) & ~255LL;
  unsigned int* edges = (unsigned int*)(ws + eoff);

  int S = 64;                      // slots per (bucket, wg) run; need ~17 MB
  if (eoff + 4LL * BKT * BKT * S > ws_size)   // ws is ~268 MB; never triggers
    S = (int)(((ws_size - eoff) / (4LL * BKT * BKT)) & ~3LL);

  k_scatter<<<BKT, 1024, 0, stream>>>(src, dst, edges, cnt2, E, NBv, Mdiv, S, chunk);
  k_degscale<<<BKT, 1024, 0, stream>>>(x, edges, cnt2, deg, dinv, xs, n, NBv, S);
  k_agg1mlp<<<BKT, 1024, 0, stream>>>(edges, cnt2, deg, dinv, xs, W1, b1, W2, ss, n, NBv, S, hidden);
  k_agg2final<<<BKT, 1024, 0, stream>>>(edges, cnt2, dinv, ss, b2, out, n, NBv, S);
}